// Round 1
// 127.097 us; speedup vs baseline: 1.0008x; 1.0008x over previous
//
#include <hip/hip_runtime.h>
#include <math.h>

// QMIX mixing network, B=65536, A=8, S=256, E=32. All tensors fp32.
// Transposed MFMA: A-operand = bf16(Wcat^T) fragments (m = out col),
// B-operand = bf16(states) (n = batch row), mfma_f32_16x16x32_bf16.
// Dual-B: each wave computes 32 batch rows; block = 128 rows (4 waves).
//
// R7: counted-vmcnt pipeline (T3/T4). __syncthreads' implicit
// s_waitcnt vmcnt(0) was draining the just-issued chunk-(k+1) prefetch DMA
// and states HBM loads every chunk -> per-chunk latency serialization.
// Now: raw s_barrier + per-wave counted vmcnt. Per-iteration issue order is
// FIXED (counts depend on it):
//   [vmcnt(n) drains D(k)+s(k)] [bar1] [f2b s(k)] [issue s(k+1), asm-pinned]
//   [MFMA on buf k&1] [lgkmcnt(0)] [bar2: WAR closed] [issue D(k+2) -> buf k&1]
// Per-wave DMA count n: waves 0,1 stage 6 tiles, waves 2,3 stage 5
// (22 tiles / 4 waves). Steady state leaves D(k+1) (n ops) in flight across
// barrier + MFMA phase; vmcnt(0) only at the last chunk.
// NOTE: counts assume no loop-body scratch spills (spills are vmcnt ops).
// Wcat columns: [0,256)=w1_W, [256,288)=wf_W, [288,320)=b1_W, [320,352)=v1_W.

#define NTILES 22      // 352/16
#define KCHUNKS 8      // 256/32
#define CHUNK_I4 1408  // 16B units per k-chunk (22528 B)

typedef __attribute__((ext_vector_type(8))) short short8;
typedef __attribute__((ext_vector_type(4))) float float4v;

__device__ __forceinline__ unsigned short f2b(float f) {
    unsigned int u = __float_as_uint(f);
    u = u + 0x7fffu + ((u >> 16) & 1u);   // RNE
    return (unsigned short)(u >> 16);
}

// Direct global->LDS DMA, 16 B/lane. LDS dest = wave-uniform base + lane*16.
__device__ __forceinline__ void gl2lds16(const unsigned short* g, unsigned short* l) {
    __builtin_amdgcn_global_load_lds(
        (const __attribute__((address_space(1))) unsigned int*)g,
        (__attribute__((address_space(3))) unsigned int*)l,
        16, 0, 0);
}

// Issue-pinned async 16B load: compiler does not model the latency (no
// auto-waitcnt), so completion is guaranteed only by our counted vmcnt.
__device__ __forceinline__ float4v ld16_async(const float* p) {
    float4v r;
    asm volatile("global_load_dwordx4 %0, %1, off" : "=v"(r) : "v"(p));
    return r;
}

// Repack fp32 Wcat into bf16 A-fragment order, slot = kc*22 + t (kc-major:
// each k-chunk is a contiguous 22528 B block — validated R2-R6):
// brep[(slot*64 + lane)*8 + j] = bf16(Wcat[k = kc*32+(lane>>4)*8+j][t*16+(lane&15)])
__global__ void repack_b(const float* __restrict__ w1_W,
                         const float* __restrict__ wf_W,
                         const float* __restrict__ b1_W,
                         const float* __restrict__ v1_W,
                         unsigned short* __restrict__ brep) {
    int idx = blockIdx.x * 256 + threadIdx.x;   // 0..11263
    int lane = idx & 63;
    int tt   = idx >> 6;          // kc*22 + t
    int t    = tt % 22;
    int kc   = tt / 22;
    int kbase = kc * 32 + (lane >> 4) * 8;
    int n = t * 16 + (lane & 15);
    short8 frag;
#pragma unroll
    for (int j = 0; j < 8; ++j) {
        int k = kbase + j;
        float val;
        if (n < 256)      val = w1_W[k * 256 + n];
        else if (n < 288) val = wf_W[k * 32 + (n - 256)];
        else if (n < 320) val = b1_W[k * 32 + (n - 288)];
        else              val = v1_W[k * 32 + (n - 320)];
        frag[j] = (short)f2b(val);
    }
    *(short8*)(&brep[idx * 8]) = frag;
}

__global__ void __launch_bounds__(256, 2)
qmix_main(const float* __restrict__ agent_qs,
          const float* __restrict__ states,
          const unsigned short* __restrict__ brep,
          const float* __restrict__ w1_b,
          const float* __restrict__ wf_b,
          const float* __restrict__ b1_b,
          const float* __restrict__ v1_b,
          const float* __restrict__ v2_W,
          const float* __restrict__ v2_b,
          float* __restrict__ out) {
    __shared__ __align__(16) unsigned short wlds[2][NTILES * 64 * 8];  // 2 x 22528 B

    const int tid  = threadIdx.x;
    const int wave = tid >> 6, lane = tid & 63;
    const int quad = lane >> 4, l16 = lane & 15;
    const int r0 = blockIdx.x * 128 + wave * 32 + l16;   // group 0 row; group 1 = +16
    const float* srow0 = states + (size_t)r0 * 256;
    const float* srow1 = srow0 + 16 * 256;

    float4v st[4];   // states fragments for the chunk about to be consumed

    // Issue order inside each macro is part of the vmcnt contract.
#define ISSUE_STATES(kcv) do {                                          \
        const float* p0_ = srow0 + (kcv) * 32 + quad * 8;               \
        const float* p1_ = srow1 + (kcv) * 32 + quad * 8;               \
        st[0] = ld16_async(p0_);                                        \
        st[1] = ld16_async(p0_ + 4);                                    \
        st[2] = ld16_async(p1_);                                        \
        st[3] = ld16_async(p1_ + 4);                                    \
    } while (0)

    // Wave w stages tiles {w, w+4, ...}: waves 0,1 -> 6 DMA ops, waves 2,3 -> 5.
#define ISSUE_DMA(kcv, bufv) do {                                       \
        const unsigned short* src_ = brep + (size_t)(kcv) * CHUNK_I4 * 8; \
        unsigned short* dst_ = wlds[bufv];                              \
        for (int s_ = wave; s_ < NTILES; s_ += 4)                       \
            gl2lds16(src_ + (size_t)(s_ * 64 + lane) * 8, dst_ + s_ * 512); \
    } while (0)

    // Prologue. Global issue order: D(0), s(0), D(1)  [then loop: s(1), D(2), ...]
    ISSUE_DMA(0, 0);
    ISSUE_STATES(0);
    ISSUE_DMA(1, 1);

    float4v acc[2][NTILES];
#pragma unroll
    for (int g = 0; g < 2; ++g)
#pragma unroll
        for (int t = 0; t < NTILES; ++t)
#pragma unroll
            for (int q = 0; q < 4; ++q) acc[g][t][q] = 0.f;

#pragma unroll
    for (int kc = 0; kc < KCHUNKS; ++kc) {
        const int buf = kc & 1;

        // Drain own D(kc) and s(kc); leave D(kc+1) (n ops) in flight.
        // Outstanding here (oldest first): D(kc):n, s(kc):4, D(kc+1):n.
        if (kc == KCHUNKS - 1)
            asm volatile("s_waitcnt vmcnt(0)" ::: "memory");
        else if (wave < 2)
            asm volatile("s_waitcnt vmcnt(6)" ::: "memory");
        else
            asm volatile("s_waitcnt vmcnt(5)" ::: "memory");
        __builtin_amdgcn_sched_barrier(0);
        __builtin_amdgcn_s_barrier();          // all waves' D(kc) landed -> buf readable
        __builtin_amdgcn_sched_barrier(0);

        // Convert current states frags to bf16 (st valid: drained above)
        short8 b0, b1;
#pragma unroll
        for (int j = 0; j < 4; ++j) {
            b0[j]     = (short)f2b(st[0][j]);
            b0[4 + j] = (short)f2b(st[1][j]);
            b1[j]     = (short)f2b(st[2][j]);
            b1[4 + j] = (short)f2b(st[3][j]);
        }
        // Prefetch next states frags (asm-pinned issue, flies across this MFMA
        // phase + barriers; consumed at next iteration's f2b after vmcnt).
        if (kc + 1 < KCHUNKS) ISSUE_STATES(kc + 1);

        // MFMA phase on current buffer: 22 ds_read_b128 feed 44 MFMAs
        const short8* wb = (const short8*)wlds[buf] + lane;
#pragma unroll
        for (int t = 0; t < NTILES; ++t) {
            short8 af = wb[t * 64];
            acc[0][t] = __builtin_amdgcn_mfma_f32_16x16x32_bf16(af, b0, acc[0][t], 0, 0, 0);
            acc[1][t] = __builtin_amdgcn_mfma_f32_16x16x32_bf16(af, b1, acc[1][t], 0, 0, 0);
        }

        // WAR close + issue D(kc+2) into the buffer we just finished reading.
        if (kc + 2 < KCHUNKS) {
            asm volatile("s_waitcnt lgkmcnt(0)" ::: "memory");
            __builtin_amdgcn_sched_barrier(0);
            __builtin_amdgcn_s_barrier();      // all waves done reading buf
            __builtin_amdgcn_sched_barrier(0);
            ISSUE_DMA(kc + 2, buf);
        }
    }

    // ---- Epilogue (per row-group, all in registers; R4-R6 verified mapping) ----
#pragma unroll
    for (int g = 0; g < 2; ++g) {
        const int row = r0 + g * 16;
        float4v q0 = *(const float4v*)(agent_qs + (size_t)row * 8);
        float4v q1 = *(const float4v*)(agent_qs + (size_t)row * 8 + 4);
        float qv[8] = {q0[0], q0[1], q0[2], q0[3], q1[0], q1[1], q1[2], q1[3]};

        float qacc[8], wfv[8], b1v[8], svp = 0.f;
#pragma unroll
        for (int s = 0; s < 8; ++s) qacc[s] = 0.f;

#pragma unroll
        for (int t = 0; t < NTILES; ++t) {
            const float* bptr =
                (t < 16) ? (w1_b + t * 16) :
                (t < 18) ? (wf_b + (t - 16) * 16) :
                (t < 20) ? (b1_b + (t - 18) * 16) : (v1_b + (t - 20) * 16);
            float4v bb = *(const float4v*)(bptr + quad * 4);
            float vb[4];
#pragma unroll
            for (int j = 0; j < 4; ++j) vb[j] = acc[g][t][j] + bb[j];

            if (t < 16) {              // w1: agent a = t>>1, slot base = (t&1)*4
                float q = qv[t >> 1];
                int base = (t & 1) * 4;
#pragma unroll
                for (int j = 0; j < 4; ++j) qacc[base + j] += q * fabsf(vb[j]);
            } else if (t < 18) {       // w_final
                int base = (t - 16) * 4;
#pragma unroll
                for (int j = 0; j < 4; ++j) wfv[base + j] = fabsf(vb[j]);
            } else if (t < 20) {       // b1
                int base = (t - 18) * 4;
#pragma unroll
                for (int j = 0; j < 4; ++j) b1v[base + j] = vb[j];
            } else {                   // V hidden: relu -> dot v2_W
                int ebase = (t - 20) * 16 + quad * 4;
#pragma unroll
                for (int j = 0; j < 4; ++j)
                    svp += fmaxf(vb[j], 0.f) * v2_W[ebase + j];
            }
        }

        float mix = 0.f;
#pragma unroll
        for (int s = 0; s < 8; ++s) {
            float h = qacc[s] + b1v[s];
            h = h > 0.f ? h : (__expf(h) - 1.f);   // elu, alpha=1
            mix += h * wfv[s];
        }
        float tot = mix + svp;                      // partial over this quad's e-subset
        tot += __shfl_xor(tot, 16);                 // combine 4 quads (same batch row)
        tot += __shfl_xor(tot, 32);
        if (quad == 0) out[row] = tot + v2_b[0];
    }
}

extern "C" void kernel_launch(void* const* d_in, const int* in_sizes, int n_in,
                              void* d_out, int out_size, void* d_ws, size_t ws_size,
                              hipStream_t stream) {
    const float* agent_qs = (const float*)d_in[0];
    const float* states   = (const float*)d_in[1];
    const float* w1_W = (const float*)d_in[2];
    const float* w1_b = (const float*)d_in[3];
    const float* wf_W = (const float*)d_in[4];
    const float* wf_b = (const float*)d_in[5];
    const float* b1_W = (const float*)d_in[6];
    const float* b1_b = (const float*)d_in[7];
    const float* v1_W = (const float*)d_in[8];
    const float* v1_b = (const float*)d_in[9];
    const float* v2_W = (const float*)d_in[10];
    const float* v2_b = (const float*)d_in[11];
    float* out = (float*)d_out;
    unsigned short* brep = (unsigned short*)d_ws;    // 180224 B of scratch

    repack_b<<<44, 256, 0, stream>>>(w1_W, wf_W, b1_W, v1_W, brep);
    qmix_main<<<512, 256, 0, stream>>>(agent_qs, states, brep,
                                       w1_b, wf_b, b1_b, v1_b, v2_W, v2_b, out);
}